// Round 2
// baseline (309.657 us; speedup 1.0000x reference)
//
#include <hip/hip_runtime.h>

typedef unsigned short u16;
typedef unsigned int   u32;
typedef short  short8v __attribute__((ext_vector_type(8)));
typedef u16    u16x8   __attribute__((ext_vector_type(8)));
typedef float  f32x16  __attribute__((ext_vector_type(16)));
typedef float  f32x4v  __attribute__((ext_vector_type(4)));
typedef u32    u32x2   __attribute__((ext_vector_type(2)));
typedef u32    u32x4   __attribute__((ext_vector_type(4)));

#define HEADS 64
#define DMODEL 128
#define SEQ 2048

// ---------- helpers ----------

__device__ __forceinline__ f32x16 mfma_bf16(short8v a, short8v b, f32x16 c) {
  return __builtin_amdgcn_mfma_f32_32x32x16_bf16(a, b, c, 0, 0, 0);
}

__device__ __forceinline__ f32x16 fzero16() {
  f32x16 z;
#pragma unroll
  for (int i = 0; i < 16; ++i) z[i] = 0.f;
  return z;
}

// round-to-nearest-even f32 -> bf16 bits
__device__ __forceinline__ u32 bfround(float x) {
  u32 u = __builtin_bit_cast(u32, x);
  u += 0x7fffu + ((u >> 16) & 1u);
  return u >> 16;
}
__device__ __forceinline__ u32 bfpair(float lo, float hi) {
  u32 a = __builtin_bit_cast(u32, lo); a += 0x7fffu + ((a >> 16) & 1u);
  u32 b = __builtin_bit_cast(u32, hi); b += 0x7fffu + ((b >> 16) & 1u);
  return (a >> 16) | (b & 0xffff0000u);
}

// Transposing stage: src is [128 d][2048 pos] f32 (row-major).
// Writes LDS tile [64 pos][128 d] bf16, 16B-chunk XOR-swizzled: chunk' = chunk ^ (row&7).
// 512 threads; each loads 8 consecutive pos from two adjacent d rows (32B runs).
__device__ __forceinline__ void stage_T(const float* __restrict__ src, int pos0,
                                        u16* lds, int tid) {
  int ic = tid & 7;          // which 8-pos chunk
  int d0 = (tid >> 3) * 2;   // even d row; thread handles d0 and d0+1
  const float* p = src + d0 * SEQ + pos0 + ic * 8;
  f32x4v xa = *reinterpret_cast<const f32x4v*>(p);
  f32x4v xb = *reinterpret_cast<const f32x4v*>(p + 4);
  f32x4v ya = *reinterpret_cast<const f32x4v*>(p + SEQ);
  f32x4v yb = *reinterpret_cast<const f32x4v*>(p + SEQ + 4);
  u32* lds32 = reinterpret_cast<u32*>(lds);
  int cc = d0 >> 3;
#pragma unroll
  for (int k = 0; k < 8; ++k) {
    int r = ic * 8 + k;                 // pos within tile
    int c2 = cc ^ (r & 7);              // swizzled 16B chunk
    float xv = (k < 4) ? xa[k & 3] : xb[k & 3];
    float yv = (k < 4) ? ya[k & 3] : yb[k & 3];
    lds32[(r * 128 + c2 * 8 + (d0 & 7)) >> 1] = bfpair(xv, yv);  // (r,d0),(r,d0+1)
  }
}

// Straight stage: V tile [128 d][64 i] bf16 from f32 [128][2048], chunk-swizzled by (d&7).
__device__ __forceinline__ void stage_V(const float* __restrict__ src, int i0,
                                        u16* lds, int tid) {
#pragma unroll
  for (int rr = 0; rr < 2; ++rr) {
    int s = tid + rr * 512;
    int d = s >> 3, ch = s & 7;
    const float* p = src + d * SEQ + i0 + ch * 8;
    f32x4v a = *reinterpret_cast<const f32x4v*>(p);
    f32x4v b = *reinterpret_cast<const f32x4v*>(p + 4);
    u32x4 v = { bfpair(a[0], a[1]), bfpair(a[2], a[3]),
                bfpair(b[0], b[1]), bfpair(b[2], b[3]) };
    int c2 = ch ^ (d & 7);
    *reinterpret_cast<u32x4*>(lds + d * 64 + c2 * 8) = v;
  }
}

// fragment reads (ds_read_b128), undoing the XOR swizzle
__device__ __forceinline__ short8v ld_at(const u16* lds, int row, int chunk) {
  return *reinterpret_cast<const short8v*>(lds + row * 128 + ((chunk ^ (row & 7)) * 8));
}
__device__ __forceinline__ short8v ld_vt(const u16* lds, int d, int chunk) {
  return *reinterpret_cast<const short8v*>(lds + d * 64 + ((chunk ^ (d & 7)) * 8));
}

// ---------- kernel 1: W transpose (f32 [2048][128] -> bf16 [128][2048]) ----------
__global__ void wtrans_kernel(const float* __restrict__ Wsrc, u16* __restrict__ Wt) {
  int e = blockIdx.x * 256 + threadIdx.x;
#pragma unroll
  for (int rr = 0; rr < 2; ++rr) {
    int o = e + rr * 131072;
    int dm = o >> 11, c = o & 2047;
    Wt[o] = (u16)bfround(Wsrc[c * 128 + dm]);
  }
}

// ---------- kernel 2: flash attention (softmax over i, per column j) ----------
// 512 blocks = head(64) x jblock(8, 256 j each), swizzled so a head's 8 jblocks
// share an XCD (L2 reuse of Q/V). 512 threads = 8 waves, 32 j per wave.
// O_ws layout: [n][j][d] bf16.
__global__ __launch_bounds__(512, 2) void attn_kernel(
    const float* __restrict__ Q, const float* __restrict__ K,
    const float* __restrict__ V, u16* __restrict__ Ows) {
  __shared__ __align__(16) u16 AT[64 * 128];   // transposed Q (or K in prologue) tile
  __shared__ __align__(16) u16 VT[128 * 64];   // V tile [d][i]
  const int tid = threadIdx.x;
  const int w = tid >> 6;
  const int lane = tid & 63;
  const int g = lane >> 5;
  const int lj = lane & 31;
  const int p_ = blockIdx.x;
  const int n = ((p_ >> 6) << 3) | (p_ & 7);   // head; p%8 == n%8 -> same XCD per head
  const int j0 = ((p_ >> 3) & 7) * 256;
  const float* Qb = Q + n * DMODEL * SEQ;
  const float* Kb = K + n * DMODEL * SEQ;
  const float* Vb = V + n * DMODEL * SEQ;

  // --- prologue: this wave's 32 K-rows (j) into registers, k(=d)-contiguous ---
  short8v bq[8];
#pragma unroll 1
  for (int p = 0; p < 4; ++p) {
    stage_T(Kb, j0 + p * 64, AT, tid);
    __syncthreads();
    if ((w >> 1) == p) {
      int row = (w & 1) * 32 + lj;
#pragma unroll
      for (int c = 0; c < 8; ++c) bq[c] = ld_at(AT, row, 2 * c + g);
    }
    __syncthreads();
  }

  f32x16 o0 = fzero16(), o1 = fzero16(), o2 = fzero16(), o3 = fzero16();
  float m_run = -1e30f, l_run = 0.f;
  const float SC = (float)(1.4426950408889634 / 11.313708498984761); // log2e/sqrt(128)

#pragma unroll 1
  for (int ib = 0; ib < 32; ++ib) {
    stage_T(Qb, ib * 64, AT, tid);   // [64 i][128 d]
    stage_V(Vb, ib * 64, VT, tid);   // [128 d][64 i]
    __syncthreads();

    // QK^T: C[i (2x32 tiles), j(32)] ; A from LDS, B(K) from registers
    f32x16 c0 = fzero16(), c1 = fzero16();
#pragma unroll
    for (int dc = 0; dc < 8; ++dc) {
      short8v a0 = ld_at(AT, lj, 2 * dc + g);
      short8v a1 = ld_at(AT, 32 + lj, 2 * dc + g);
      c0 = mfma_bf16(a0, bq[dc], c0);
      c1 = mfma_bf16(a1, bq[dc], c1);
    }

    // online softmax over i for column j = lj (state replicated on lane pair l, l^32)
    float mx = -1e30f;
#pragma unroll
    for (int r = 0; r < 16; ++r) { c0[r] *= SC; mx = fmaxf(mx, c0[r]); }
#pragma unroll
    for (int r = 0; r < 16; ++r) { c1[r] *= SC; mx = fmaxf(mx, c1[r]); }
    mx = fmaxf(mx, __shfl_xor(mx, 32, 64));
    float mn = fmaxf(m_run, mx);
    float al = exp2f(m_run - mn);
    m_run = mn;
    float ps = 0.f;
#pragma unroll
    for (int r = 0; r < 16; ++r) { c0[r] = exp2f(c0[r] - mn); ps += c0[r]; }
#pragma unroll
    for (int r = 0; r < 16; ++r) { c1[r] = exp2f(c1[r] - mn); ps += c1[r]; }
    ps += __shfl_xor(ps, 32, 64);
    l_run = l_run * al + ps;
#pragma unroll
    for (int r = 0; r < 16; ++r) { o0[r] *= al; o1[r] *= al; o2[r] *= al; o3[r] *= al; }

    // pack P to bf16 pairs; exchange halves so each lane can build B-frags (k=i)
    u32 pk[16], ok[16];
#pragma unroll
    for (int q = 0; q < 4; ++q) {
#pragma unroll
      for (int h = 0; h < 2; ++h) {
        pk[q * 2 + h]     = bfpair(c0[q * 4 + 2 * h], c0[q * 4 + 2 * h + 1]);
        pk[8 + q * 2 + h] = bfpair(c1[q * 4 + 2 * h], c1[q * 4 + 2 * h + 1]);
      }
    }
#pragma unroll
    for (int i = 0; i < 16; ++i) ok[i] = __shfl_xor(pk[i], 32, 64);

    // PV: O[d(4x32 tiles), j] += V[d,i] * P[i,j]
#pragma unroll
    for (int kc = 0; kc < 4; ++kc) {
      const int base = (kc >> 1) * 8 + 4 * (kc & 1);
      u32 w0 = g ? ok[base + 2] : pk[base + 0];
      u32 w1 = g ? ok[base + 3] : pk[base + 1];
      u32 w2 = g ? pk[base + 2] : ok[base + 0];
      u32 w3 = g ? pk[base + 3] : ok[base + 1];
      u32x4 uu = {w0, w1, w2, w3};
      short8v pf = __builtin_bit_cast(short8v, uu);
      short8v v0 = ld_vt(VT, lj,      2 * kc + g);
      short8v v1 = ld_vt(VT, 32 + lj, 2 * kc + g);
      short8v v2 = ld_vt(VT, 64 + lj, 2 * kc + g);
      short8v v3 = ld_vt(VT, 96 + lj, 2 * kc + g);
      o0 = mfma_bf16(v0, pf, o0);
      o1 = mfma_bf16(v1, pf, o1);
      o2 = mfma_bf16(v2, pf, o2);
      o3 = mfma_bf16(v3, pf, o3);
    }
    __syncthreads();
  }

  // epilogue: O /= l, store bf16 to Ows[n][j][d]
  float inv = 1.f / l_run;
  int jme = j0 + w * 32 + lj;
  u16* obase = Ows + ((size_t)n * SEQ + jme) * DMODEL;

#define STORE_OT(OV, DT)                                                  \
  {                                                                       \
    _Pragma("unroll") for (int q = 0; q < 4; ++q) {                       \
      int d0 = (DT) * 32 + 4 * g + 8 * q;                                 \
      u32x2 val;                                                          \
      val.x = bfpair(OV[4 * q + 0] * inv, OV[4 * q + 1] * inv);           \
      val.y = bfpair(OV[4 * q + 2] * inv, OV[4 * q + 3] * inv);           \
      *reinterpret_cast<u32x2*>(obase + d0) = val;                        \
    }                                                                     \
  }
  STORE_OT(o0, 0) STORE_OT(o1, 1) STORE_OT(o2, 2) STORE_OT(o3, 3)
#undef STORE_OT
}

// ---------- kernel 3: projection out[b][dm][j] = sum_c Wt[dm][c] * Ows[b,c][j] ----
// grid 256 = b(4) x jtile(64, 32 j each); 256 threads = 4 waves (one 32-dm tile each)
__global__ __launch_bounds__(256) void proj_kernel(
    const u16* __restrict__ Ows, const u16* __restrict__ Wt, float* __restrict__ out) {
  __shared__ __align__(16) u16 BT[32 * 128];
  const int tid = threadIdx.x;
  const int w = tid >> 6, lane = tid & 63, g = lane >> 5, lj = lane & 31;
  const int b = blockIdx.x >> 6;
  const int j0 = (blockIdx.x & 63) * 32;
  f32x16 acc = fzero16();
#pragma unroll 1
  for (int h = 0; h < 16; ++h) {
    __syncthreads();
#pragma unroll
    for (int rr = 0; rr < 2; ++rr) {
      int s = tid + rr * 256;
      int r = s >> 4, cc = s & 15;
      u16x8 v = *reinterpret_cast<const u16x8*>(
          Ows + ((size_t)(b * 16 + h) * SEQ + j0 + r) * DMODEL + cc * 8);
      *reinterpret_cast<u16x8*>(BT + r * 128 + ((cc ^ (r & 7)) * 8)) = v;
    }
    __syncthreads();
#pragma unroll
    for (int kc = 0; kc < 8; ++kc) {
      short8v a = *reinterpret_cast<const short8v*>(
          Wt + (size_t)(w * 32 + lj) * SEQ + h * 128 + kc * 16 + g * 8);
      short8v bb = *reinterpret_cast<const short8v*>(
          BT + lj * 128 + (((2 * kc + g) ^ (lj & 7)) * 8));
      acc = mfma_bf16(a, bb, acc);
    }
  }
#pragma unroll
  for (int q = 0; q < 4; ++q) {
#pragma unroll
    for (int r = 0; r < 4; ++r) {
      int dm = w * 32 + 4 * g + 8 * q + r;
      out[((size_t)b * DMODEL + dm) * SEQ + j0 + lj] = acc[4 * q + r];
    }
  }
}

// ---------- host launcher ----------
extern "C" void kernel_launch(void* const* d_in, const int* in_sizes, int n_in,
                              void* d_out, int out_size, void* d_ws, size_t ws_size,
                              hipStream_t stream) {
  (void)in_sizes; (void)n_in; (void)out_size; (void)ws_size;
  // inputs: 0=x (unused, shape only), 1=Q, 2=K, 3=V, 4=W  -- all float32 on device
  const float* Q = (const float*)d_in[1];
  const float* K = (const float*)d_in[2];
  const float* V = (const float*)d_in[3];
  const float* W = (const float*)d_in[4];
  u16* Ows = (u16*)d_ws;                                  // 64*2048*128 bf16 = 32 MB
  u16* Wt  = Ows + (size_t)HEADS * SEQ * DMODEL;          // 128*2048 bf16 = 0.5 MB
  float* out = (float*)d_out;

  wtrans_kernel<<<dim3(512), dim3(256), 0, stream>>>(W, Wt);
  attn_kernel<<<dim3(512), dim3(512), 0, stream>>>(Q, K, V, Ows);
  proj_kernel<<<dim3(256), dim3(256), 0, stream>>>(Ows, Wt, out);
}